// Round 9
// baseline (134.145 us; speedup 1.0000x reference)
//
#include <hip/hip_runtime.h>

#define L_SEQ 4096
#define DMODEL 256
#define DH 64
#define NKB 16   // key blocks (of 64) per workgroup: 4096 / 64 / ksplit(4)

typedef __attribute__((ext_vector_type(8))) __bf16 bf16x8;
typedef __attribute__((ext_vector_type(4))) float f32x4;
typedef __attribute__((ext_vector_type(16))) float f32x16;
typedef __attribute__((ext_vector_type(8))) unsigned short ushort8v;
typedef __attribute__((ext_vector_type(4))) unsigned short ushort4v;
typedef __attribute__((ext_vector_type(2))) unsigned int uint2v;
typedef __attribute__((ext_vector_type(4))) unsigned int uint4v;

__device__ __forceinline__ unsigned short f2bf(float f) {
  unsigned u = __builtin_bit_cast(unsigned, f);
  u += 0x7fffu + ((u >> 16) & 1u);
  return (unsigned short)(u >> 16);
}
__device__ __forceinline__ float bf2f(unsigned short h) {
  unsigned u = ((unsigned)h) << 16;
  return __builtin_bit_cast(float, u);
}
__device__ __forceinline__ bf16x8 ld_frag(const unsigned short* p) {
  return __builtin_bit_cast(bf16x8, *(const ushort8v*)p);
}
// pack 2 f32 -> 2 bf16 (RNE, same rounding as f2bf) in one VALU op
__device__ __forceinline__ unsigned cvtpk(float lo, float hi) {
  unsigned r;
  asm("v_cvt_pk_bf16_f32 %0, %1, %2" : "=v"(r) : "v"(lo), "v"(hi));
  return r;
}
// a.hi32lanes <-> b.lo32lanes (v_permlane32_swap_b32, gfx950)
__device__ __forceinline__ void plswap(unsigned& a, unsigned& b) {
  asm("v_permlane32_swap_b32 %0, %1" : "+v"(a), "+v"(b));
}
// raw v_exp_f32: D = 2^S0 (saves __expf's hidden *log2e mul; R5/R7/R8-verified)
__device__ __forceinline__ float exp2raw(float x) {
  float r;
  asm("v_exp_f32 %0, %1" : "=v"(r) : "v"(x));
  return r;
}

// ---- 1. q [B,C,L] fp32 -> xbf [B*L, C] bf16; blocks >=512 convert weights ----
// (R8-exact)
__global__ __launch_bounds__(256) void k_transpose(const float* __restrict__ q,
                                                   unsigned short* __restrict__ xbf,
                                                   const float* __restrict__ w,
                                                   const float* __restrict__ fcw,
                                                   unsigned short* __restrict__ wbf,
                                                   unsigned short* __restrict__ fcwbf) {
  int bx = blockIdx.x;
  int t = threadIdx.x;
  if (bx >= 512) {   // weight conversion tail
    int i = ((bx - 512) * 256 + t) * 4;
    float4 a = *(const float4*)(w + i);
    float4 b = *(const float4*)(fcw + i);
    ushort4v av = {f2bf(a.x), f2bf(a.y), f2bf(a.z), f2bf(a.w)};
    ushort4v bv = {f2bf(b.x), f2bf(b.y), f2bf(b.z), f2bf(b.w)};
    *(ushort4v*)(wbf + i) = av;
    *(ushort4v*)(fcwbf + i) = bv;
    return;
  }
  __shared__ float T[64 * 65];
  int b = bx >> 8, rest = bx & 255;
  int ct = rest >> 6, lt = rest & 63;
#pragma unroll
  for (int it = 0; it < 4; ++it) {
    int i = (t >> 4) + it * 16;
    int j0 = (t & 15) * 4;
    float4 v = *(const float4*)(q + ((size_t)(b * 256 + ct * 64 + i)) * 4096 + lt * 64 + j0);
    T[i * 65 + j0 + 0] = v.x;
    T[i * 65 + j0 + 1] = v.y;
    T[i * 65 + j0 + 2] = v.z;
    T[i * 65 + j0 + 3] = v.w;
  }
  __syncthreads();
#pragma unroll
  for (int it = 0; it < 2; ++it) {
    int l = (t >> 3) + it * 32;
    int c0 = (t & 7) * 8;
    ushort8v o;
#pragma unroll
    for (int k = 0; k < 8; ++k) o[k] = f2bf(T[(c0 + k) * 65 + l]);
    *(ushort8v*)(xbf + ((size_t)(b * 4096 + lt * 64 + l)) * 256 + ct * 64 + c0) = o;
  }
}

// ---- 2. QKV GEMM -> Qh [p][l][d] and QhT [p][d][l].
// R9: software-pipelined staging — kb+1's global loads issue right after the
// barrier that publishes kb's tiles, hiding load latency under the MFMAs
// (the pattern k_attn has used since R0). Math/layout identical to R8.
#define KP2 136
__global__ __launch_bounds__(256) void k_qkv(const unsigned short* __restrict__ xbf,
                                             const unsigned short* __restrict__ wbf,
                                             unsigned short* __restrict__ Qh,
                                             unsigned short* __restrict__ QhT) {
  __shared__ unsigned short As[64 * KP2];
  __shared__ unsigned short Bs[64 * KP2];
  int bx = blockIdx.x;
  int mtile = bx >> 2, h = bx & 3;
  int m0 = mtile * 64;
  int b = m0 >> 12, l0 = m0 & 4095;
  int t = threadIdx.x;
  int wv = t >> 6, lane = t & 63, g = lane >> 4, ln = lane & 15;
  f32x4 acc[4] = {};
  ushort8v a_reg[4], b_reg[4];
#pragma unroll
  for (int it = 0; it < 4; ++it) {   // prefetch kb=0
    int idx = t + it * 256;
    int row = idx >> 4;
    int c0 = (idx & 15) * 8;
    a_reg[it] = *(const ushort8v*)(xbf + (size_t)(m0 + row) * 256 + c0);
    b_reg[it] = *(const ushort8v*)(wbf + (size_t)(h * 64 + row) * 256 + c0);
  }
  for (int kb = 0; kb < 2; ++kb) {
#pragma unroll
    for (int it = 0; it < 4; ++it) {
      int idx = t + it * 256;
      int row = idx >> 4;
      int c0 = (idx & 15) * 8;
      *(ushort8v*)(As + row * KP2 + c0) = a_reg[it];
      *(ushort8v*)(Bs + row * KP2 + c0) = b_reg[it];
    }
    __syncthreads();
    if (kb == 0) {   // prefetch kb=1 under the MFMAs
#pragma unroll
      for (int it = 0; it < 4; ++it) {
        int idx = t + it * 256;
        int row = idx >> 4;
        int c0 = (idx & 15) * 8;
        a_reg[it] = *(const ushort8v*)(xbf + (size_t)(m0 + row) * 256 + 128 + c0);
        b_reg[it] = *(const ushort8v*)(wbf + (size_t)(h * 64 + row) * 256 + 128 + c0);
      }
    }
#pragma unroll
    for (int kc = 0; kc < 4; ++kc) {
      bf16x8 a = ld_frag(As + (wv * 16 + ln) * KP2 + kc * 32 + g * 8);
#pragma unroll
      for (int tn = 0; tn < 4; ++tn) {
        bf16x8 bb = ld_frag(Bs + (tn * 16 + ln) * KP2 + kc * 32 + g * 8);
        acc[tn] = __builtin_amdgcn_mfma_f32_16x16x32_bf16(a, bb, acc[tn], 0, 0, 0);
      }
    }
    __syncthreads();
  }
  size_t pbase = (size_t)(b * 4 + h);
  // ---- epilogue: bounce tiles through LDS, then dense 16-B stores ----
#pragma unroll
  for (int tn = 0; tn < 4; ++tn) {
#pragma unroll
    for (int r = 0; r < 4; ++r) {
      int lrow = wv * 16 + g * 4 + r;
      int d = tn * 16 + ln;
      unsigned short bv = f2bf(acc[tn][r]);
      As[lrow * 64 + (((d >> 3) ^ (lrow & 7)) * 8) + (d & 7)] = bv;
      Bs[d * 64 + (((lrow >> 3) ^ (d & 7)) * 8) + (lrow & 7)] = bv;
    }
  }
#pragma unroll
  for (int s = 0; s < 2; ++s) {
    int flat = s * 64 + lane;
    int lrow = wv * 16 + (flat >> 3);
    int c8 = lane & 7;
    ushort8v v = *(const ushort8v*)(As + lrow * 64 + ((c8 ^ (lrow & 7)) * 8));
    *(ushort8v*)(Qh + (pbase * L_SEQ + l0 + lrow) * DH + c8 * 8) = v;
  }
  __syncthreads();
#pragma unroll
  for (int s = 0; s < 2; ++s) {
    int flat = s * 256 + t;
    int drow = flat >> 3;
    int c8 = t & 7;
    ushort8v v = *(const ushort8v*)(Bs + drow * 64 + ((c8 ^ (drow & 7)) * 8));
    *(ushort8v*)(QhT + (pbase * DH + drow) * L_SEQ + l0 + c8 * 8) = v;
  }
}

// ---- 3. flash attention (R8-exact: q-split + exp2raw + setprio, 49.6us) ----
__global__ __launch_bounds__(256, 2) void k_attn(const unsigned short* __restrict__ Qh,
                                                 const unsigned short* __restrict__ QhT,
                                                 unsigned short* __restrict__ Opart,
                                                 float* __restrict__ Lpart) {
  constexpr float C1 = 0.18033688011112042f;   // 0.125 * log2(e)
  constexpr float C2 = -23.083120654223414f;   // -16 * log2(e)
  __shared__ unsigned short smem[4 * 4096];  // K0 V0 K1 V1, 8KB each, 32 KB
  int bx = blockIdx.x;
  int p = bx & 7;
  int u = bx >> 3;
  int qsup = u & 31, ks = u >> 5;
  int t = threadIdx.x;
  int wv = t >> 6, lane = t & 63, ln = lane & 31, hi = lane >> 5;
  const unsigned short* Qp = Qh + (size_t)p * L_SEQ * DH;
  const unsigned short* QTp = QhT + (size_t)p * DH * L_SEQ;
  int q0 = qsup * 128;
  int qw = q0 + wv * 32;  // this wave's 32 q rows

  bf16x8 aQ[4];
#pragma unroll
  for (int kq = 0; kq < 4; ++kq)
    aQ[kq] = ld_frag(Qp + (size_t)(qw + ln) * DH + kq * 16 + hi * 8);

  f32x16 oacc[2] = {};   // [dt], O^T fragments
  float lacc = 0.f;      // per-lane partial l (half the keys)

  int srow0 = t >> 3, scol = t & 7;
  int srow1 = srow0 + 32;
  int sdst0 = srow0 * 64 + ((scol ^ (srow0 & 7)) * 8);
  int sdst1 = srow1 * 64 + ((scol ^ (srow1 & 7)) * 8);

  ushort8v kreg0, kreg1, vreg0, vreg1;
  {
    int kbase = (ks * NKB) * 64;
    kreg0 = *(const ushort8v*)(Qp + (size_t)(kbase + srow0) * DH + scol * 8);
    kreg1 = *(const ushort8v*)(Qp + (size_t)(kbase + srow1) * DH + scol * 8);
    vreg0 = *(const ushort8v*)(QTp + (size_t)srow0 * L_SEQ + kbase + scol * 8);
    vreg1 = *(const ushort8v*)(QTp + (size_t)srow1 * L_SEQ + kbase + scol * 8);
  }

  for (int kb = 0; kb < NKB; ++kb) {
    unsigned short* Kc = smem + (kb & 1) * 8192;
    unsigned short* Vc = Kc + 4096;
    // write buf[kb&1]: safe — its last readers (compute kb-2) are gated by
    // barrier(kb-1), which every wave passed before reaching this write.
    *(ushort8v*)(Kc + sdst0) = kreg0;
    *(ushort8v*)(Kc + sdst1) = kreg1;
    *(ushort8v*)(Vc + sdst0) = vreg0;
    *(ushort8v*)(Vc + sdst1) = vreg1;
    __syncthreads();
    if (kb + 1 < NKB) {  // issue next tile's loads; land during compute
      int kbase = (ks * NKB + kb + 1) * 64;
      kreg0 = *(const ushort8v*)(Qp + (size_t)(kbase + srow0) * DH + scol * 8);
      kreg1 = *(const ushort8v*)(Qp + (size_t)(kbase + srow1) * DH + scol * 8);
      vreg0 = *(const ushort8v*)(QTp + (size_t)srow0 * L_SEQ + kbase + scol * 8);
      vreg1 = *(const ushort8v*)(QTp + (size_t)srow1 * L_SEQ + kbase + scol * 8);
    }
#pragma unroll
    for (int mt = 0; mt < 2; ++mt) {
      int key = mt * 32 + ln;
      bf16x8 aK[4];
#pragma unroll
      for (int kq = 0; kq < 4; ++kq)
        aK[kq] = ld_frag(Kc + key * 64 + (((kq * 2 + hi) ^ (key & 7)) * 8));
      f32x16 s = {};
      __builtin_amdgcn_s_setprio(1);
#pragma unroll
      for (int kq = 0; kq < 4; ++kq)
        s = __builtin_amdgcn_mfma_f32_32x32x16_bf16(aK[kq], aQ[kq], s, 0, 0, 0);
      __builtin_amdgcn_s_setprio(0);
      // fixed-max softmax: p = 2^(s*C1 + C2) == exp(s/8 - 16)
      float pv[16];
#pragma unroll
      for (int r = 0; r < 16; ++r) pv[r] = exp2raw(fmaf(s[r], C1, C2));
      lacc += (((pv[0] + pv[1]) + (pv[2] + pv[3])) + ((pv[4] + pv[5]) + (pv[6] + pv[7]))) +
              (((pv[8] + pv[9]) + (pv[10] + pv[11])) + ((pv[12] + pv[13]) + (pv[14] + pv[15])));
      unsigned w0 = cvtpk(pv[0], pv[1]), w1 = cvtpk(pv[2], pv[3]);
      unsigned w2 = cvtpk(pv[4], pv[5]), w3 = cvtpk(pv[6], pv[7]);
      unsigned w4 = cvtpk(pv[8], pv[9]), w5 = cvtpk(pv[10], pv[11]);
      unsigned w6 = cvtpk(pv[12], pv[13]), w7 = cvtpk(pv[14], pv[15]);
      plswap(w0, w2);  // after: w0 = keys{lo:0,1 | hi:8,9}, w2 = {lo:4,5 | hi:12,13}
      plswap(w1, w3);  //        w1 = {lo:2,3 | hi:10,11}, w3 = {lo:6,7 | hi:14,15}
      plswap(w4, w6);  // same for keys 16..31 (chunk 1)
      plswap(w5, w7);
      uint4v c0 = {w0, w1, w2, w3};
      uint4v c1 = {w4, w5, w6, w7};
      bf16x8 pf0 = __builtin_bit_cast(bf16x8, c0);
      bf16x8 pf1 = __builtin_bit_cast(bf16x8, c1);
#pragma unroll
      for (int dt = 0; dt < 2; ++dt) {
        int d = dt * 32 + ln;
        bf16x8 vf0 = ld_frag(Vc + d * 64 + (((mt * 4 + 0 * 2 + hi) ^ (d & 7)) * 8));
        bf16x8 vf1 = ld_frag(Vc + d * 64 + (((mt * 4 + 1 * 2 + hi) ^ (d & 7)) * 8));
        __builtin_amdgcn_s_setprio(1);
        oacc[dt] = __builtin_amdgcn_mfma_f32_32x32x16_bf16(vf0, pf0, oacc[dt], 0, 0, 0);
        oacc[dt] = __builtin_amdgcn_mfma_f32_32x32x16_bf16(vf1, pf1, oacc[dt], 0, 0, 0);
        __builtin_amdgcn_s_setprio(0);
      }
    }
  }
  lacc += __shfl_xor(lacc, 32, 64);
  size_t pq = (size_t)(ks * 8 + p) * L_SEQ;
  if (lane < 32) Lpart[pq + qw + ln] = lacc;
  // O^T epilogue (verified): lane owns q = qw+ln;
  // reg r -> d = dt*32 + (r>>2)*8 + hi*4 + (r&3); cvt_pk pairs -> 8B stores.
#pragma unroll
  for (int dt = 0; dt < 2; ++dt) {
    size_t rb = (pq + qw + ln) * DH + dt * 32 + hi * 4;
#pragma unroll
    for (int g8 = 0; g8 < 4; ++g8) {
      uint2v wv2 = {cvtpk(oacc[dt][g8 * 4 + 0], oacc[dt][g8 * 4 + 1]),
                    cvtpk(oacc[dt][g8 * 4 + 2], oacc[dt][g8 * 4 + 3])};
      *(uint2v*)(Opart + rb + g8 * 8) = wv2;
    }
  }
}

// ---- 4. FC GEMM (fused ks-merge) + bias + residual + LayerNorm.
// R9: software-pipelined — kb+1's Lpart/Opart/fcw loads (8+8 per thread,
// previously serial on the critical path each iteration) now issue right
// after kb's tiles are published, overlapping the MFMAs. Math identical.
#define CP 72
__global__ __launch_bounds__(256) void k_fc(const unsigned short* __restrict__ Opart,
                                            const float* __restrict__ Lpart,
                                            const unsigned short* __restrict__ fcwbf,
                                            const float* __restrict__ qres,
                                            const float* __restrict__ fcb,
                                            const float* __restrict__ lng,
                                            const float* __restrict__ lnb,
                                            float* __restrict__ out) {
  __shared__ unsigned short As[32 * CP];
  __shared__ unsigned short Bs[256 * CP];
  __shared__ float redS[4][32], redQ[4][32], muA[32], rsA[32];
  int bx = blockIdx.x;
  int m0 = bx * 32;
  int b = m0 >> 12, lpart = m0 & 4095;
  int t = threadIdx.x;
  int wv = t >> 6, lane = t & 63, g = lane >> 4, ln = lane & 15;
  int arow = t >> 3, ac0 = (t & 7) * 8;
  int aq = lpart + arow;
  f32x4 acc[2][4] = {};
  float l_reg[4];
  ushort8v o_reg[4];
  ushort8v bw_reg[8];
  {  // prefetch kb=0
    int p = b * 4;
#pragma unroll
    for (int i = 0; i < 4; ++i) l_reg[i] = Lpart[(size_t)(i * 8 + p) * L_SEQ + aq];
#pragma unroll
    for (int ksp = 0; ksp < 4; ++ksp)
      o_reg[ksp] = *(const ushort8v*)(Opart + ((size_t)(ksp * 8 + p) * L_SEQ + aq) * DH + ac0);
#pragma unroll
    for (int it = 0; it < 8; ++it) {
      int idx = t + it * 256;
      int row = idx >> 3, c0 = (idx & 7) * 8;
      bw_reg[it] = *(const ushort8v*)(fcwbf + (size_t)row * 256 + c0);
    }
  }
  for (int kb = 0; kb < 4; ++kb) {   // kb == head index
    {
      float lsum = (l_reg[0] + l_reg[1]) + (l_reg[2] + l_reg[3]);
      float inv = 1.0f / lsum;
      float a8[8] = {0.f, 0.f, 0.f, 0.f, 0.f, 0.f, 0.f, 0.f};
#pragma unroll
      for (int ksp = 0; ksp < 4; ++ksp)
#pragma unroll
        for (int j = 0; j < 8; ++j) a8[j] += bf2f(o_reg[ksp][j]);
      ushort8v o;
#pragma unroll
      for (int j = 0; j < 8; ++j) o[j] = f2bf(a8[j] * inv);
      *(ushort8v*)(As + arow * CP + ac0) = o;
#pragma unroll
      for (int it = 0; it < 8; ++it) {
        int idx = t + it * 256;
        int row = idx >> 3, c0 = (idx & 7) * 8;
        *(ushort8v*)(Bs + row * CP + c0) = bw_reg[it];
      }
    }
    __syncthreads();
    if (kb < 3) {   // prefetch kb+1 under the MFMAs
      int p = b * 4 + kb + 1;
#pragma unroll
      for (int i = 0; i < 4; ++i) l_reg[i] = Lpart[(size_t)(i * 8 + p) * L_SEQ + aq];
#pragma unroll
      for (int ksp = 0; ksp < 4; ++ksp)
        o_reg[ksp] = *(const ushort8v*)(Opart + ((size_t)(ksp * 8 + p) * L_SEQ + aq) * DH + ac0);
#pragma unroll
      for (int it = 0; it < 8; ++it) {
        int idx = t + it * 256;
        int row = idx >> 3, c0 = (idx & 7) * 8;
        bw_reg[it] = *(const ushort8v*)(fcwbf + (size_t)row * 256 + (kb + 1) * 64 + c0);
      }
    }
#pragma unroll
    for (int kc = 0; kc < 2; ++kc) {
      bf16x8 a[2], bb[4];
#pragma unroll
      for (int mt = 0; mt < 2; ++mt) a[mt] = ld_frag(As + (mt * 16 + ln) * CP + kc * 32 + g * 8);
#pragma unroll
      for (int tn = 0; tn < 4; ++tn) bb[tn] = ld_frag(Bs + (wv * 64 + tn * 16 + ln) * CP + kc * 32 + g * 8);
#pragma unroll
      for (int mt = 0; mt < 2; ++mt)
#pragma unroll
        for (int tn = 0; tn < 4; ++tn)
          acc[mt][tn] = __builtin_amdgcn_mfma_f32_16x16x32_bf16(a[mt], bb[tn], acc[mt][tn], 0, 0, 0);
    }
    __syncthreads();
  }
  float fb[4], lg[4], lb[4];
#pragma unroll
  for (int tn = 0; tn < 4; ++tn) {
    int o = wv * 64 + tn * 16 + ln;
    fb[tn] = fcb[o]; lg[tn] = lng[o]; lb[tn] = lnb[o];
  }
#pragma unroll
  for (int mt = 0; mt < 2; ++mt) {
    float ps[4] = {0.f, 0.f, 0.f, 0.f}, pq2[4] = {0.f, 0.f, 0.f, 0.f};
#pragma unroll
    for (int tn = 0; tn < 4; ++tn) {
      int o = wv * 64 + tn * 16 + ln;
      float4 res = *(const float4*)(qres + ((size_t)(b * 256 + o)) * 4096 + lpart + mt * 16 + g * 4);
      float rv[4] = {res.x, res.y, res.z, res.w};
#pragma unroll
      for (int r = 0; r < 4; ++r) {
        float v = acc[mt][tn][r] + fb[tn] + rv[r];
        acc[mt][tn][r] = v;
        ps[r] += v;
        pq2[r] += v * v;
      }
    }
#pragma unroll
    for (int r = 0; r < 4; ++r) {
      float s = ps[r], q2 = pq2[r];
#pragma unroll
      for (int off = 1; off < 16; off <<= 1) {
        s += __shfl_xor(s, off, 64);
        q2 += __shfl_xor(q2, off, 64);
      }
      if (ln == 0) {
        int row = mt * 16 + g * 4 + r;
        redS[wv][row] = s;
        redQ[wv][row] = q2;
      }
    }
  }
  __syncthreads();
  if (t < 32) {
    float s = redS[0][t] + redS[1][t] + redS[2][t] + redS[3][t];
    float q2 = redQ[0][t] + redQ[1][t] + redQ[2][t] + redQ[3][t];
    float mu = s * (1.f / 256.f);
    float var = q2 * (1.f / 256.f) - mu * mu;
    muA[t] = mu;
    rsA[t] = rsqrtf(var + 1e-5f);
  }
  __syncthreads();
#pragma unroll
  for (int mt = 0; mt < 2; ++mt) {
#pragma unroll
    for (int r = 0; r < 4; ++r) {
      int row = mt * 16 + g * 4 + r;
      float mu = muA[row], rs = rsA[row];
#pragma unroll
      for (int tn = 0; tn < 4; ++tn) {
        int o = wv * 64 + tn * 16 + ln;
        out[(size_t)(m0 + row) * 256 + o] = (acc[mt][tn][r] - mu) * rs * lg[tn] + lb[tn];
      }
    }
  }
}

extern "C" void kernel_launch(void* const* d_in, const int* in_sizes, int n_in,
                              void* d_out, int out_size, void* d_ws, size_t ws_size,
                              hipStream_t stream) {
  const float* q = (const float*)d_in[0];
  const float* w_qkv = (const float*)d_in[1];
  const float* fc_w = (const float*)d_in[2];
  const float* fc_b = (const float*)d_in[3];
  const float* ln_g = (const float*)d_in[4];
  const float* ln_b = (const float*)d_in[5];
  float* out = (float*)d_out;

  unsigned short* wbf = (unsigned short*)d_ws;   // 65536
  unsigned short* fcwbf = wbf + 65536;           // 65536
  unsigned short* xbf = fcwbf + 65536;           // 8192*256
  unsigned short* Qh = xbf + 2097152;            // [p][l][d]
  unsigned short* QhT = Qh + 2097152;            // [p][d][l]
  unsigned short* Opart = QhT + 2097152;         // [ks][p][q][d] bf16, 4*2M
  float* Lpart = (float*)(Opart + 8388608);      // [ks][p][q] fp32
  // total ws use: ~30.1 MB

  k_transpose<<<dim3(576), dim3(256), 0, stream>>>(q, xbf, w_qkv, fc_w, wbf, fcwbf);
  k_qkv<<<dim3(512), dim3(256), 0, stream>>>(xbf, wbf, Qh, QhT);
  k_attn<<<dim3(1024), dim3(256), 0, stream>>>(Qh, QhT, Opart, Lpart);
  k_fc<<<dim3(256), dim3(256), 0, stream>>>(Opart, Lpart, fcwbf, q, fc_b, ln_g, ln_b, out);
}

// Round 10
// 130.098 us; speedup vs baseline: 1.0311x; 1.0311x over previous
//
#include <hip/hip_runtime.h>

#define L_SEQ 4096
#define DMODEL 256
#define DH 64
#define NKB 32   // key blocks (of 64) per workgroup: 4096 / 64 / ksplit(2)

typedef __attribute__((ext_vector_type(8))) __bf16 bf16x8;
typedef __attribute__((ext_vector_type(4))) float f32x4;
typedef __attribute__((ext_vector_type(16))) float f32x16;
typedef __attribute__((ext_vector_type(8))) unsigned short ushort8v;
typedef __attribute__((ext_vector_type(4))) unsigned short ushort4v;
typedef __attribute__((ext_vector_type(2))) unsigned int uint2v;
typedef __attribute__((ext_vector_type(4))) unsigned int uint4v;

__device__ __forceinline__ unsigned short f2bf(float f) {
  unsigned u = __builtin_bit_cast(unsigned, f);
  u += 0x7fffu + ((u >> 16) & 1u);
  return (unsigned short)(u >> 16);
}
__device__ __forceinline__ float bf2f(unsigned short h) {
  unsigned u = ((unsigned)h) << 16;
  return __builtin_bit_cast(float, u);
}
__device__ __forceinline__ bf16x8 ld_frag(const unsigned short* p) {
  return __builtin_bit_cast(bf16x8, *(const ushort8v*)p);
}
// pack 2 f32 -> 2 bf16 (RNE, same rounding as f2bf) in one VALU op
__device__ __forceinline__ unsigned cvtpk(float lo, float hi) {
  unsigned r;
  asm("v_cvt_pk_bf16_f32 %0, %1, %2" : "=v"(r) : "v"(lo), "v"(hi));
  return r;
}
// a.hi32lanes <-> b.lo32lanes (v_permlane32_swap_b32, gfx950)
__device__ __forceinline__ void plswap(unsigned& a, unsigned& b) {
  asm("v_permlane32_swap_b32 %0, %1" : "+v"(a), "+v"(b));
}
// raw v_exp_f32: D = 2^S0 (saves __expf's hidden *log2e mul; R5/R7/R8-verified)
__device__ __forceinline__ float exp2raw(float x) {
  float r;
  asm("v_exp_f32 %0, %1" : "=v"(r) : "v"(x));
  return r;
}

// ---- 1. q [B,C,L] fp32 -> xbf [B*L, C] bf16; blocks >=512 convert weights ----
// (R8-exact)
__global__ __launch_bounds__(256) void k_transpose(const float* __restrict__ q,
                                                   unsigned short* __restrict__ xbf,
                                                   const float* __restrict__ w,
                                                   const float* __restrict__ fcw,
                                                   unsigned short* __restrict__ wbf,
                                                   unsigned short* __restrict__ fcwbf) {
  int bx = blockIdx.x;
  int t = threadIdx.x;
  if (bx >= 512) {   // weight conversion tail
    int i = ((bx - 512) * 256 + t) * 4;
    float4 a = *(const float4*)(w + i);
    float4 b = *(const float4*)(fcw + i);
    ushort4v av = {f2bf(a.x), f2bf(a.y), f2bf(a.z), f2bf(a.w)};
    ushort4v bv = {f2bf(b.x), f2bf(b.y), f2bf(b.z), f2bf(b.w)};
    *(ushort4v*)(wbf + i) = av;
    *(ushort4v*)(fcwbf + i) = bv;
    return;
  }
  __shared__ float T[64 * 65];
  int b = bx >> 8, rest = bx & 255;
  int ct = rest >> 6, lt = rest & 63;
#pragma unroll
  for (int it = 0; it < 4; ++it) {
    int i = (t >> 4) + it * 16;
    int j0 = (t & 15) * 4;
    float4 v = *(const float4*)(q + ((size_t)(b * 256 + ct * 64 + i)) * 4096 + lt * 64 + j0);
    T[i * 65 + j0 + 0] = v.x;
    T[i * 65 + j0 + 1] = v.y;
    T[i * 65 + j0 + 2] = v.z;
    T[i * 65 + j0 + 3] = v.w;
  }
  __syncthreads();
#pragma unroll
  for (int it = 0; it < 2; ++it) {
    int l = (t >> 3) + it * 32;
    int c0 = (t & 7) * 8;
    ushort8v o;
#pragma unroll
    for (int k = 0; k < 8; ++k) o[k] = f2bf(T[(c0 + k) * 65 + l]);
    *(ushort8v*)(xbf + ((size_t)(b * 4096 + lt * 64 + l)) * 256 + ct * 64 + c0) = o;
  }
}

// ---- 2. QKV GEMM -> Qh [p][l][d] and QhT [p][d][l] (R8-exact) ----
#define KP2 136
__global__ __launch_bounds__(256) void k_qkv(const unsigned short* __restrict__ xbf,
                                             const unsigned short* __restrict__ wbf,
                                             unsigned short* __restrict__ Qh,
                                             unsigned short* __restrict__ QhT) {
  __shared__ unsigned short As[64 * KP2];
  __shared__ unsigned short Bs[64 * KP2];
  int bx = blockIdx.x;
  int mtile = bx >> 2, h = bx & 3;
  int m0 = mtile * 64;
  int b = m0 >> 12, l0 = m0 & 4095;
  int t = threadIdx.x;
  int wv = t >> 6, lane = t & 63, g = lane >> 4, ln = lane & 15;
  f32x4 acc[4] = {};
  for (int kb = 0; kb < 2; ++kb) {
#pragma unroll
    for (int it = 0; it < 4; ++it) {
      int idx = t + it * 256;
      int row = idx >> 4;
      int c0 = (idx & 15) * 8;
      *(ushort8v*)(As + row * KP2 + c0) =
          *(const ushort8v*)(xbf + (size_t)(m0 + row) * 256 + kb * 128 + c0);
      *(ushort8v*)(Bs + row * KP2 + c0) =
          *(const ushort8v*)(wbf + (size_t)(h * 64 + row) * 256 + kb * 128 + c0);
    }
    __syncthreads();
#pragma unroll
    for (int kc = 0; kc < 4; ++kc) {
      bf16x8 a = ld_frag(As + (wv * 16 + ln) * KP2 + kc * 32 + g * 8);
#pragma unroll
      for (int tn = 0; tn < 4; ++tn) {
        bf16x8 bb = ld_frag(Bs + (tn * 16 + ln) * KP2 + kc * 32 + g * 8);
        acc[tn] = __builtin_amdgcn_mfma_f32_16x16x32_bf16(a, bb, acc[tn], 0, 0, 0);
      }
    }
    __syncthreads();
  }
  size_t pbase = (size_t)(b * 4 + h);
  // ---- epilogue: bounce tiles through LDS, then dense 16-B stores ----
#pragma unroll
  for (int tn = 0; tn < 4; ++tn) {
#pragma unroll
    for (int r = 0; r < 4; ++r) {
      int lrow = wv * 16 + g * 4 + r;
      int d = tn * 16 + ln;
      unsigned short bv = f2bf(acc[tn][r]);
      As[lrow * 64 + (((d >> 3) ^ (lrow & 7)) * 8) + (d & 7)] = bv;
      Bs[d * 64 + (((lrow >> 3) ^ (d & 7)) * 8) + (lrow & 7)] = bv;
    }
  }
#pragma unroll
  for (int s = 0; s < 2; ++s) {
    int flat = s * 64 + lane;
    int lrow = wv * 16 + (flat >> 3);
    int c8 = lane & 7;
    ushort8v v = *(const ushort8v*)(As + lrow * 64 + ((c8 ^ (lrow & 7)) * 8));
    *(ushort8v*)(Qh + (pbase * L_SEQ + l0 + lrow) * DH + c8 * 8) = v;
  }
  __syncthreads();
#pragma unroll
  for (int s = 0; s < 2; ++s) {
    int flat = s * 256 + t;
    int drow = flat >> 3;
    int c8 = t & 7;
    ushort8v v = *(const ushort8v*)(Bs + drow * 64 + ((c8 ^ (drow & 7)) * 8));
    *(ushort8v*)(QhT + (pbase * DH + drow) * L_SEQ + l0 + c8 * 8) = v;
  }
}

// ---- 3. flash attention (R8-exact body; key-split 4->2).
// R4/R6 proved occupancy is not the k_attn lever (shape-invariant ~50us), so
// ks=4's only remaining effect was 2x Opart partial traffic. ks=2: grid
// 512 = exactly 2 wg/CU (same resident waves as measured), NKB=32,
// Opart/Lpart halve. grid 512 = 8p x 32qsup x 2ks.
__global__ __launch_bounds__(256, 2) void k_attn(const unsigned short* __restrict__ Qh,
                                                 const unsigned short* __restrict__ QhT,
                                                 unsigned short* __restrict__ Opart,
                                                 float* __restrict__ Lpart) {
  constexpr float C1 = 0.18033688011112042f;   // 0.125 * log2(e)
  constexpr float C2 = -23.083120654223414f;   // -16 * log2(e)
  __shared__ unsigned short smem[4 * 4096];  // K0 V0 K1 V1, 8KB each, 32 KB
  int bx = blockIdx.x;
  int p = bx & 7;
  int u = bx >> 3;
  int qsup = u & 31, ks = u >> 5;   // ks in {0,1}
  int t = threadIdx.x;
  int wv = t >> 6, lane = t & 63, ln = lane & 31, hi = lane >> 5;
  const unsigned short* Qp = Qh + (size_t)p * L_SEQ * DH;
  const unsigned short* QTp = QhT + (size_t)p * DH * L_SEQ;
  int q0 = qsup * 128;
  int qw = q0 + wv * 32;  // this wave's 32 q rows

  bf16x8 aQ[4];
#pragma unroll
  for (int kq = 0; kq < 4; ++kq)
    aQ[kq] = ld_frag(Qp + (size_t)(qw + ln) * DH + kq * 16 + hi * 8);

  f32x16 oacc[2] = {};   // [dt], O^T fragments
  float lacc = 0.f;      // per-lane partial l (half the keys)

  int srow0 = t >> 3, scol = t & 7;
  int srow1 = srow0 + 32;
  int sdst0 = srow0 * 64 + ((scol ^ (srow0 & 7)) * 8);
  int sdst1 = srow1 * 64 + ((scol ^ (srow1 & 7)) * 8);

  ushort8v kreg0, kreg1, vreg0, vreg1;
  {
    int kbase = (ks * NKB) * 64;
    kreg0 = *(const ushort8v*)(Qp + (size_t)(kbase + srow0) * DH + scol * 8);
    kreg1 = *(const ushort8v*)(Qp + (size_t)(kbase + srow1) * DH + scol * 8);
    vreg0 = *(const ushort8v*)(QTp + (size_t)srow0 * L_SEQ + kbase + scol * 8);
    vreg1 = *(const ushort8v*)(QTp + (size_t)srow1 * L_SEQ + kbase + scol * 8);
  }

  for (int kb = 0; kb < NKB; ++kb) {
    unsigned short* Kc = smem + (kb & 1) * 8192;
    unsigned short* Vc = Kc + 4096;
    // write buf[kb&1]: safe — its last readers (compute kb-2) are gated by
    // barrier(kb-1), which every wave passed before reaching this write.
    *(ushort8v*)(Kc + sdst0) = kreg0;
    *(ushort8v*)(Kc + sdst1) = kreg1;
    *(ushort8v*)(Vc + sdst0) = vreg0;
    *(ushort8v*)(Vc + sdst1) = vreg1;
    __syncthreads();
    if (kb + 1 < NKB) {  // issue next tile's loads; land during compute
      int kbase = (ks * NKB + kb + 1) * 64;
      kreg0 = *(const ushort8v*)(Qp + (size_t)(kbase + srow0) * DH + scol * 8);
      kreg1 = *(const ushort8v*)(Qp + (size_t)(kbase + srow1) * DH + scol * 8);
      vreg0 = *(const ushort8v*)(QTp + (size_t)srow0 * L_SEQ + kbase + scol * 8);
      vreg1 = *(const ushort8v*)(QTp + (size_t)srow1 * L_SEQ + kbase + scol * 8);
    }
#pragma unroll
    for (int mt = 0; mt < 2; ++mt) {
      int key = mt * 32 + ln;
      bf16x8 aK[4];
#pragma unroll
      for (int kq = 0; kq < 4; ++kq)
        aK[kq] = ld_frag(Kc + key * 64 + (((kq * 2 + hi) ^ (key & 7)) * 8));
      f32x16 s = {};
      __builtin_amdgcn_s_setprio(1);
#pragma unroll
      for (int kq = 0; kq < 4; ++kq)
        s = __builtin_amdgcn_mfma_f32_32x32x16_bf16(aK[kq], aQ[kq], s, 0, 0, 0);
      __builtin_amdgcn_s_setprio(0);
      // fixed-max softmax: p = 2^(s*C1 + C2) == exp(s/8 - 16)
      float pv[16];
#pragma unroll
      for (int r = 0; r < 16; ++r) pv[r] = exp2raw(fmaf(s[r], C1, C2));
      lacc += (((pv[0] + pv[1]) + (pv[2] + pv[3])) + ((pv[4] + pv[5]) + (pv[6] + pv[7]))) +
              (((pv[8] + pv[9]) + (pv[10] + pv[11])) + ((pv[12] + pv[13]) + (pv[14] + pv[15])));
      unsigned w0 = cvtpk(pv[0], pv[1]), w1 = cvtpk(pv[2], pv[3]);
      unsigned w2 = cvtpk(pv[4], pv[5]), w3 = cvtpk(pv[6], pv[7]);
      unsigned w4 = cvtpk(pv[8], pv[9]), w5 = cvtpk(pv[10], pv[11]);
      unsigned w6 = cvtpk(pv[12], pv[13]), w7 = cvtpk(pv[14], pv[15]);
      plswap(w0, w2);  // after: w0 = keys{lo:0,1 | hi:8,9}, w2 = {lo:4,5 | hi:12,13}
      plswap(w1, w3);  //        w1 = {lo:2,3 | hi:10,11}, w3 = {lo:6,7 | hi:14,15}
      plswap(w4, w6);  // same for keys 16..31 (chunk 1)
      plswap(w5, w7);
      uint4v c0 = {w0, w1, w2, w3};
      uint4v c1 = {w4, w5, w6, w7};
      bf16x8 pf0 = __builtin_bit_cast(bf16x8, c0);
      bf16x8 pf1 = __builtin_bit_cast(bf16x8, c1);
#pragma unroll
      for (int dt = 0; dt < 2; ++dt) {
        int d = dt * 32 + ln;
        bf16x8 vf0 = ld_frag(Vc + d * 64 + (((mt * 4 + 0 * 2 + hi) ^ (d & 7)) * 8));
        bf16x8 vf1 = ld_frag(Vc + d * 64 + (((mt * 4 + 1 * 2 + hi) ^ (d & 7)) * 8));
        __builtin_amdgcn_s_setprio(1);
        oacc[dt] = __builtin_amdgcn_mfma_f32_32x32x16_bf16(vf0, pf0, oacc[dt], 0, 0, 0);
        oacc[dt] = __builtin_amdgcn_mfma_f32_32x32x16_bf16(vf1, pf1, oacc[dt], 0, 0, 0);
        __builtin_amdgcn_s_setprio(0);
      }
    }
  }
  lacc += __shfl_xor(lacc, 32, 64);
  size_t pq = (size_t)(ks * 8 + p) * L_SEQ;
  if (lane < 32) Lpart[pq + qw + ln] = lacc;
  // O^T epilogue (verified): lane owns q = qw+ln;
  // reg r -> d = dt*32 + (r>>2)*8 + hi*4 + (r&3); cvt_pk pairs -> 8B stores.
#pragma unroll
  for (int dt = 0; dt < 2; ++dt) {
    size_t rb = (pq + qw + ln) * DH + dt * 32 + hi * 4;
#pragma unroll
    for (int g8 = 0; g8 < 4; ++g8) {
      uint2v wv2 = {cvtpk(oacc[dt][g8 * 4 + 0], oacc[dt][g8 * 4 + 1]),
                    cvtpk(oacc[dt][g8 * 4 + 2], oacc[dt][g8 * 4 + 3])};
      *(uint2v*)(Opart + rb + g8 * 8) = wv2;
    }
  }
}

// ---- 4. FC GEMM (fused ks-merge, now 2-way) + bias + residual + LayerNorm
// (R8-exact body; only the ksp merge width changed 4->2) ----
#define CP 72
__global__ __launch_bounds__(256) void k_fc(const unsigned short* __restrict__ Opart,
                                            const float* __restrict__ Lpart,
                                            const unsigned short* __restrict__ fcwbf,
                                            const float* __restrict__ qres,
                                            const float* __restrict__ fcb,
                                            const float* __restrict__ lng,
                                            const float* __restrict__ lnb,
                                            float* __restrict__ out) {
  __shared__ unsigned short As[32 * CP];
  __shared__ unsigned short Bs[256 * CP];
  __shared__ float redS[4][32], redQ[4][32], muA[32], rsA[32];
  int bx = blockIdx.x;
  int m0 = bx * 32;
  int b = m0 >> 12, lpart = m0 & 4095;
  int t = threadIdx.x;
  int wv = t >> 6, lane = t & 63, g = lane >> 4, ln = lane & 15;
  f32x4 acc[2][4] = {};
  for (int kb = 0; kb < 4; ++kb) {   // kb == head index for A-staging
    {
      int row = t >> 3, c0 = (t & 7) * 8;
      int q = lpart + row;
      int p = b * 4 + kb;
      float lsum = Lpart[(size_t)(0 * 8 + p) * L_SEQ + q] +
                   Lpart[(size_t)(1 * 8 + p) * L_SEQ + q];
      float inv = 1.0f / lsum;
      float a8[8] = {0.f, 0.f, 0.f, 0.f, 0.f, 0.f, 0.f, 0.f};
#pragma unroll
      for (int ksp = 0; ksp < 2; ++ksp) {
        ushort8v v = *(const ushort8v*)(Opart + ((size_t)(ksp * 8 + p) * L_SEQ + q) * DH + c0);
#pragma unroll
        for (int j = 0; j < 8; ++j) a8[j] += bf2f(v[j]);
      }
      ushort8v o;
#pragma unroll
      for (int j = 0; j < 8; ++j) o[j] = f2bf(a8[j] * inv);
      *(ushort8v*)(As + row * CP + c0) = o;
    }
#pragma unroll
    for (int it = 0; it < 8; ++it) {
      int idx = t + it * 256;
      int row = idx >> 3, c0 = (idx & 7) * 8;
      *(ushort8v*)(Bs + row * CP + c0) =
          *(const ushort8v*)(fcwbf + (size_t)row * 256 + kb * 64 + c0);
    }
    __syncthreads();
#pragma unroll
    for (int kc = 0; kc < 2; ++kc) {
      bf16x8 a[2], bb[4];
#pragma unroll
      for (int mt = 0; mt < 2; ++mt) a[mt] = ld_frag(As + (mt * 16 + ln) * CP + kc * 32 + g * 8);
#pragma unroll
      for (int tn = 0; tn < 4; ++tn) bb[tn] = ld_frag(Bs + (wv * 64 + tn * 16 + ln) * CP + kc * 32 + g * 8);
#pragma unroll
      for (int mt = 0; mt < 2; ++mt)
#pragma unroll
        for (int tn = 0; tn < 4; ++tn)
          acc[mt][tn] = __builtin_amdgcn_mfma_f32_16x16x32_bf16(a[mt], bb[tn], acc[mt][tn], 0, 0, 0);
    }
    __syncthreads();
  }
  float fb[4], lg[4], lb[4];
#pragma unroll
  for (int tn = 0; tn < 4; ++tn) {
    int o = wv * 64 + tn * 16 + ln;
    fb[tn] = fcb[o]; lg[tn] = lng[o]; lb[tn] = lnb[o];
  }
#pragma unroll
  for (int mt = 0; mt < 2; ++mt) {
    float ps[4] = {0.f, 0.f, 0.f, 0.f}, pq2[4] = {0.f, 0.f, 0.f, 0.f};
#pragma unroll
    for (int tn = 0; tn < 4; ++tn) {
      int o = wv * 64 + tn * 16 + ln;
      float4 res = *(const float4*)(qres + ((size_t)(b * 256 + o)) * 4096 + lpart + mt * 16 + g * 4);
      float rv[4] = {res.x, res.y, res.z, res.w};
#pragma unroll
      for (int r = 0; r < 4; ++r) {
        float v = acc[mt][tn][r] + fb[tn] + rv[r];
        acc[mt][tn][r] = v;
        ps[r] += v;
        pq2[r] += v * v;
      }
    }
#pragma unroll
    for (int r = 0; r < 4; ++r) {
      float s = ps[r], q2 = pq2[r];
#pragma unroll
      for (int off = 1; off < 16; off <<= 1) {
        s += __shfl_xor(s, off, 64);
        q2 += __shfl_xor(q2, off, 64);
      }
      if (ln == 0) {
        int row = mt * 16 + g * 4 + r;
        redS[wv][row] = s;
        redQ[wv][row] = q2;
      }
    }
  }
  __syncthreads();
  if (t < 32) {
    float s = redS[0][t] + redS[1][t] + redS[2][t] + redS[3][t];
    float q2 = redQ[0][t] + redQ[1][t] + redQ[2][t] + redQ[3][t];
    float mu = s * (1.f / 256.f);
    float var = q2 * (1.f / 256.f) - mu * mu;
    muA[t] = mu;
    rsA[t] = rsqrtf(var + 1e-5f);
  }
  __syncthreads();
#pragma unroll
  for (int mt = 0; mt < 2; ++mt) {
#pragma unroll
    for (int r = 0; r < 4; ++r) {
      int row = mt * 16 + g * 4 + r;
      float mu = muA[row], rs = rsA[row];
#pragma unroll
      for (int tn = 0; tn < 4; ++tn) {
        int o = wv * 64 + tn * 16 + ln;
        out[(size_t)(m0 + row) * 256 + o] = (acc[mt][tn][r] - mu) * rs * lg[tn] + lb[tn];
      }
    }
  }
}

extern "C" void kernel_launch(void* const* d_in, const int* in_sizes, int n_in,
                              void* d_out, int out_size, void* d_ws, size_t ws_size,
                              hipStream_t stream) {
  const float* q = (const float*)d_in[0];
  const float* w_qkv = (const float*)d_in[1];
  const float* fc_w = (const float*)d_in[2];
  const float* fc_b = (const float*)d_in[3];
  const float* ln_g = (const float*)d_in[4];
  const float* ln_b = (const float*)d_in[5];
  float* out = (float*)d_out;

  unsigned short* wbf = (unsigned short*)d_ws;   // 65536
  unsigned short* fcwbf = wbf + 65536;           // 65536
  unsigned short* xbf = fcwbf + 65536;           // 8192*256
  unsigned short* Qh = xbf + 2097152;            // [p][l][d]
  unsigned short* QhT = Qh + 2097152;            // [p][d][l]
  unsigned short* Opart = QhT + 2097152;         // [ks][p][q][d] bf16, 2*2M shorts
  float* Lpart = (float*)(Opart + 4194304);      // [ks][p][q] fp32, 64K floats
  // total ws use: ~21.5 MB

  k_transpose<<<dim3(576), dim3(256), 0, stream>>>(q, xbf, w_qkv, fc_w, wbf, fcwbf);
  k_qkv<<<dim3(512), dim3(256), 0, stream>>>(xbf, wbf, Qh, QhT);
  k_attn<<<dim3(512), dim3(256), 0, stream>>>(Qh, QhT, Opart, Lpart);
  k_fc<<<dim3(256), dim3(256), 0, stream>>>(Opart, Lpart, fcwbf, q, fc_b, ln_g, ln_b, out);
}